// Round 6
// baseline (72.266 us; speedup 1.0000x reference)
//
#include <hip/hip_runtime.h>
#include <hip/hip_bf16.h>
#include <float.h>

// GraphSAGE fused single kernel (R6): masked-max agg + ReLU + concat + Linear,
// all fp32, one block (4 waves, 256 thr) per node -> 2048 blocks = 8/CU =
// 32 waves/CU (full latency hiding for the L2 feature gathers).
//
//   phase 1: wave w ballot-compacts + max-scans neighbor quarter
//            [128w, 128w+128) of this node's adjacency row.
//   phase 1b: wave 0 combines 4 partial maxima, relu, loads self row,
//            writes fp32 combined row [self(128)|neigh(128)] to LDS.
//   phase 2: thread t computes out col (t&127) over k-half (t>>7):
//            128 FMA, s_comb[k] = LDS broadcast, W loads coalesced+L2-hot.
//            Halves summed via LDS, + bias. fp32 end-to-end (absmax ~1e-6).
//
// R5 lesson: fusing across nodes (256 big blocks) dropped occupancy to
// 8 waves/CU and was ~5us slower than R4's split kernels. This keeps R4's
// agg occupancy AND single-dispatch fusion.

#define Bsz 4
#define Nn  512
#define Cc  128
#define OUTn 128
#define NNODES (Bsz * Nn)   // 2048
#define KK (2 * Cc)         // 256

__global__ __launch_bounds__(256) void sage_fused(
    const float* __restrict__ adj,
    const float* __restrict__ feat,
    const float* __restrict__ W,      // fp32 [256][128]
    const float* __restrict__ bias,   // fp32 [128]
    float* __restrict__ out)          // fp32 [2048][128]
{
    const int w = threadIdx.x >> 6;   // 0..3
    const int l = threadIdx.x & 63;
    const int node = blockIdx.x;
    const int b = node >> 9;
    const int i = node & (Nn - 1);

    __shared__ unsigned short nbr[4][128];  // per-wave compacted indices
    __shared__ float2 pmax[4][64];          // per-wave partial max (ch pairs)
    __shared__ float  s_comb[KK];           // fp32 combined row
    __shared__ float  s_part[2][OUTn];      // half-K partial dots

    // ---- phase 1: wave w scans neighbor quarter [w*128, w*128+128) ----
    const float* adjrow = adj + (size_t)node * Nn;
    const float2* f2 = (const float2*)(feat + (size_t)b * Nn * Cc);

    int cnt = 0;
    #pragma unroll
    for (int ch = 0; ch < 2; ++ch) {
        int j = w * 128 + ch * 64 + l;
        float a = adjrow[j];
        unsigned long long mask = __ballot(a > 0.0f);
        int pos = __popcll(mask & ((1ull << l) - 1ull));
        if (a > 0.0f) nbr[w][cnt + pos] = (unsigned short)j;
        cnt += __popcll(mask);
    }
    // Same-wave DS write->read: HW lgkmcnt ordering guarantees visibility.

    float m0 = -FLT_MAX, m1 = -FLT_MAX;
    int k = 0;
    for (; k + 4 <= cnt; k += 4) {
        int j0 = nbr[w][k + 0], j1 = nbr[w][k + 1];
        int j2 = nbr[w][k + 2], j3 = nbr[w][k + 3];
        float2 v0 = f2[j0 * 64 + l];
        float2 v1 = f2[j1 * 64 + l];
        float2 v2 = f2[j2 * 64 + l];
        float2 v3 = f2[j3 * 64 + l];
        m0 = fmaxf(m0, fmaxf(fmaxf(v0.x, v1.x), fmaxf(v2.x, v3.x)));
        m1 = fmaxf(m1, fmaxf(fmaxf(v0.y, v1.y), fmaxf(v2.y, v3.y)));
    }
    for (; k < cnt; ++k) {
        int j = nbr[w][k];
        float2 v = f2[j * 64 + l];
        m0 = fmaxf(m0, v.x);
        m1 = fmaxf(m1, v.y);
    }
    pmax[w][l] = make_float2(m0, m1);
    __syncthreads();

    // ---- phase 1b: wave 0 combines, relu, self, -> s_comb (fp32) ----
    if (w == 0) {
        float2 p0 = pmax[0][l], p1 = pmax[1][l], p2 = pmax[2][l], p3 = pmax[3][l];
        float n0 = fmaxf(fmaxf(p0.x, p1.x), fmaxf(p2.x, p3.x));
        float n1 = fmaxf(fmaxf(p0.y, p1.y), fmaxf(p2.y, p3.y));
        // relu(max) also maps the no-neighbor case (-FLT_MAX) to 0, matching
        // the reference (finfo.min is finite; its isfinite-guard never fires).
        n0 = fmaxf(n0, 0.0f);
        n1 = fmaxf(n1, 0.0f);
        float2 s = f2[i * 64 + l];
        ((float2*)s_comb)[l]      = s;                   // self  ch 2l,2l+1
        ((float2*)s_comb)[64 + l] = make_float2(n0, n1); // neigh ch 128+2l,+1
    }
    __syncthreads();

    // ---- phase 2: Linear. t -> col n = t&127, k-half h = t>>7. ----
    const int n = threadIdx.x & (OUTn - 1);
    const int h = threadIdx.x >> 7;          // 0 or 1
    const float* wp = W + (size_t)h * 128 * OUTn + n;

    float acc = 0.0f;
    #pragma unroll 8
    for (int kk = 0; kk < 128; ++kk) {
        acc = fmaf(s_comb[h * 128 + kk], wp[(size_t)kk * OUTn], acc);
    }
    s_part[h][n] = acc;
    __syncthreads();

    if (threadIdx.x < OUTn) {
        out[(size_t)node * OUTn + n] = s_part[0][n] + s_part[1][n] + bias[n];
    }
}

extern "C" void kernel_launch(void* const* d_in, const int* in_sizes, int n_in,
                              void* d_out, int out_size, void* d_ws, size_t ws_size,
                              hipStream_t stream) {
    const float* adj  = (const float*)d_in[0];
    const float* feat = (const float*)d_in[1];
    const float* W    = (const float*)d_in[2];
    const float* bias = (const float*)d_in[3];
    float* out = (float*)d_out;

    sage_fused<<<dim3(NNODES), dim3(256), 0, stream>>>(adj, feat, W, bias, out);
}

// Round 7
// 68.348 us; speedup vs baseline: 1.0573x; 1.0573x over previous
//
#include <hip/hip_runtime.h>
#include <hip/hip_bf16.h>
#include <float.h>

// GraphSAGE: masked-max agg + ReLU + concat + Linear(256->128).
// B=4, N=512, C=128, OUT=128.
//
// R7 structure (best-known R4 two-kernel split, both halves tuned):
//  K1 sage_agg : 2048 agg blocks (4 waves/node, quarter-row each -> 32
//     waves/CU) with 8-wide PADDED gather rounds (dup-index padding, max is
//     idempotent -> branch-free, 8 loads in flight). PLUS 16 extra blocks
//     that convert W fp32 -> Wt bf16 [128][256] (no separate prep dispatch).
//  K2 sage_gemm: MFMA 16x16x32 bf16, A/B frags both contiguous b128 global
//     loads (comb row-major, Wt n-major). 1024 tiles, 256 blocks.
//
// Lessons: R5 (fuse across nodes) lost occupancy; R6 (VALU linear) re-read
// 256 MB of W. Keep MFMA + split kernels.

#define Bsz 4
#define Nn  512
#define Cc  128
#define OUTn 128
#define NNODES (Bsz * Nn)   // 2048
#define KK (2 * Cc)         // 256
#define PREP_BLOCKS 16      // Wt conversion blocks appended to agg grid

typedef __bf16 bf16x8 __attribute__((ext_vector_type(8)));
typedef float  f32x4  __attribute__((ext_vector_type(4)));

static __device__ __forceinline__ unsigned short f2bf(float x) {
    __hip_bfloat16 h = __float2bfloat16(x);
    return *reinterpret_cast<unsigned short*>(&h);
}

// ---- K1: aggregation + (in extra blocks) W transpose/convert -------------
__global__ __launch_bounds__(256) void sage_agg(
    const float* __restrict__ adj,
    const float* __restrict__ feat,
    const float* __restrict__ W,          // fp32 [256][128]
    unsigned short* __restrict__ comb,    // bf16 [2048][256] out
    unsigned short* __restrict__ Wt)      // bf16 [128][256]  out
{
    const int bid = blockIdx.x;

    if (bid >= NNODES) {
        // ---- Wt prep: 16 blocks x 256 thr x 8 elems = 32768 = 256*128 ----
        int base = (bid - NNODES) * 2048 + threadIdx.x * 8;
        #pragma unroll
        for (int e = 0; e < 8; ++e) {
            int idx = base + e;           // row-major over W [k][n]
            int kk = idx >> 7;
            int n  = idx & (OUTn - 1);
            Wt[n * KK + kk] = f2bf(W[idx]);
        }
        return;
    }

    // ---- aggregation: wave w scans neighbor quarter [128w, 128w+128) ----
    const int w = threadIdx.x >> 6;
    const int l = threadIdx.x & 63;
    const int node = bid;
    const int b = node >> 9;
    const int i = node & (Nn - 1);

    __shared__ unsigned short nbr[4][128];  // per-wave compacted indices
    __shared__ float2 pmax[4][64];          // per-wave partial maxima

    const float* adjrow = adj + (size_t)node * Nn;
    const float2* f2 = (const float2*)(feat + (size_t)b * Nn * Cc);

    int cnt = 0;
    #pragma unroll
    for (int ch = 0; ch < 2; ++ch) {
        int j = w * 128 + ch * 64 + l;
        float a = adjrow[j];
        unsigned long long mask = __ballot(a > 0.0f);
        int pos = __popcll(mask & ((1ull << l) - 1ull));
        if (a > 0.0f) nbr[w][cnt + pos] = (unsigned short)j;
        cnt += __popcll(mask);
    }
    // Pad index list to a multiple of 8 with a duplicate (max is idempotent)
    // -> branch-free 8-wide gather rounds below. Same-wave DS ordering makes
    // the writes visible to the reads.
    if (cnt > 0) {
        unsigned short p0 = nbr[w][0];
        int padded = (cnt + 7) & ~7;
        if (l < padded - cnt) nbr[w][cnt + l] = p0;
        cnt = padded;
    }

    float m0 = -FLT_MAX, m1 = -FLT_MAX;
    for (int k = 0; k < cnt; k += 8) {
        int j0 = nbr[w][k + 0], j1 = nbr[w][k + 1];
        int j2 = nbr[w][k + 2], j3 = nbr[w][k + 3];
        int j4 = nbr[w][k + 4], j5 = nbr[w][k + 5];
        int j6 = nbr[w][k + 6], j7 = nbr[w][k + 7];
        float2 v0 = f2[j0 * 64 + l];
        float2 v1 = f2[j1 * 64 + l];
        float2 v2 = f2[j2 * 64 + l];
        float2 v3 = f2[j3 * 64 + l];
        float2 v4 = f2[j4 * 64 + l];
        float2 v5 = f2[j5 * 64 + l];
        float2 v6 = f2[j6 * 64 + l];
        float2 v7 = f2[j7 * 64 + l];
        m0 = fmaxf(m0, fmaxf(fmaxf(fmaxf(v0.x, v1.x), fmaxf(v2.x, v3.x)),
                             fmaxf(fmaxf(v4.x, v5.x), fmaxf(v6.x, v7.x))));
        m1 = fmaxf(m1, fmaxf(fmaxf(fmaxf(v0.y, v1.y), fmaxf(v2.y, v3.y)),
                             fmaxf(fmaxf(v4.y, v5.y), fmaxf(v6.y, v7.y))));
    }
    pmax[w][l] = make_float2(m0, m1);
    __syncthreads();

    // Wave 0: combine partials, relu, load self, store bf16 comb row.
    if (w == 0) {
        float2 p0 = pmax[0][l], p1 = pmax[1][l], p2 = pmax[2][l], p3 = pmax[3][l];
        float n0 = fmaxf(fmaxf(p0.x, p1.x), fmaxf(p2.x, p3.x));
        float n1 = fmaxf(fmaxf(p0.y, p1.y), fmaxf(p2.y, p3.y));
        // relu(max) maps no-neighbor (-FLT_MAX) to 0, matching the reference
        // (finfo.min is finite, so its isfinite-guard never fires).
        n0 = fmaxf(n0, 0.0f);
        n1 = fmaxf(n1, 0.0f);
        float2 s = f2[i * 64 + l];

        ushort2* crow = (ushort2*)(comb + (size_t)node * KK);
        ushort2 sv; sv.x = f2bf(s.x); sv.y = f2bf(s.y);
        ushort2 nv; nv.x = f2bf(n0);  nv.y = f2bf(n1);
        crow[l]      = sv;   // self  channels [2l, 2l+1]
        crow[64 + l] = nv;   // neigh channels [128+2l, 128+2l+1]
    }
}

// ---- K2: GEMM  out[2048][128] = comb[2048][256] @ W[256][128] + bias ----
// One 16x16 tile per wave, K=256 in 8 mfma_f32_16x16x32_bf16 steps.
// A-frag: lane holds A[m=lane&15][k=koff+j]  -> contiguous 16B in comb row.
// B-frag: lane holds B[k=koff+j][n=lane&15]  -> contiguous 16B in Wt row.
// C/D:    col = lane&15, row = (lane>>4)*4 + reg   [measured m89/m91]
__global__ __launch_bounds__(256) void sage_gemm(
    const __bf16* __restrict__ A,    // comb bf16 [2048][256]
    const __bf16* __restrict__ Bt,   // Wt   bf16 [128][256]
    const float* __restrict__ bias,
    float* __restrict__ out)
{
    const int wave = threadIdx.x >> 6;
    const int lane = threadIdx.x & 63;
    const int tile = blockIdx.x * 4 + wave;   // 0..1023
    const int nt = tile & 7;                  // 8 n-tiles
    const int mt = tile >> 3;                 // 128 m-tiles

    const int frow = lane & 15;
    const int koff = (lane >> 4) * 8;

    const __bf16* pa = A  + (size_t)(mt * 16 + frow) * KK + koff;
    const __bf16* pb = Bt + (size_t)(nt * 16 + frow) * KK + koff;

    f32x4 acc = {0.f, 0.f, 0.f, 0.f};
    #pragma unroll
    for (int ks = 0; ks < KK / 32; ++ks) {
        bf16x8 af = *(const bf16x8*)(pa + ks * 32);
        bf16x8 bf = *(const bf16x8*)(pb + ks * 32);
        acc = __builtin_amdgcn_mfma_f32_16x16x32_bf16(af, bf, acc, 0, 0, 0);
    }

    const int col = lane & 15;            // n within tile
    const int r0  = (lane >> 4) * 4;      // m within tile
    const float bv = bias[nt * 16 + col];
    #pragma unroll
    for (int r = 0; r < 4; ++r) {
        out[(size_t)(mt * 16 + r0 + r) * OUTn + nt * 16 + col] = acc[r] + bv;
    }
}

extern "C" void kernel_launch(void* const* d_in, const int* in_sizes, int n_in,
                              void* d_out, int out_size, void* d_ws, size_t ws_size,
                              hipStream_t stream) {
    const float* adj  = (const float*)d_in[0];
    const float* feat = (const float*)d_in[1];
    const float* W    = (const float*)d_in[2];
    const float* bias = (const float*)d_in[3];
    float* out = (float*)d_out;

    unsigned short* comb = (unsigned short*)d_ws;        // 2048*256*2 = 1 MB
    unsigned short* Wt   = comb + (size_t)NNODES * KK;   // 128*256*2 = 64 KB

    sage_agg <<<dim3(NNODES + PREP_BLOCKS), dim3(256), 0, stream>>>(
        adj, feat, W, comb, Wt);
    // 1024 tiles (128 mt x 8 nt), 4 waves/block -> 256 blocks.
    sage_gemm<<<dim3(NNODES / 16 * (OUTn / 16) / 4), dim3(256), 0, stream>>>(
        (const __bf16*)comb, (const __bf16*)Wt, bias, out);
}